// Round 8
// baseline (12403.445 us; speedup 1.0000x reference)
//
#include <hip/hip_runtime.h>
#include <hip/hip_bf16.h>
#include <math.h>

// ---------------------------------------------------------------------------
// Classifier_with_Augmentation: NTS-Net-style pipeline.
//  outputs (flat float32 in d_out):
//   labels 16x200 @0 | win_scores 16x7 @3200 | win_logits 112x200 @3312
//   indices 16x7 @25712 | all_scores 16x602 @25824 | coordinates 16x7x4 @35456
// ---------------------------------------------------------------------------

#define OFF_LAB 0
#define OFF_WSC 3200
#define OFF_LOG 3312
#define OFF_IDX 25712
#define OFF_ALL 25824
#define OFF_CRD 35456

#define BS 256

static inline int cdiv(int a, int b) { return (a + b - 1) / b; }

// ---- window geometry ------------------------------------------------------
__device__ __forceinline__ void win_decode(int w, int& rh, int& rw, int& r, int& c) {
  const int RH[6] = {4, 3, 5, 6, 5, 7};
  const int RW[6] = {4, 5, 3, 6, 7, 5};
  int rem = w;
#pragma unroll
  for (int i = 0; i < 6; ++i) {
    int nc = 15 - RW[i];
    int cnt = (15 - RH[i]) * nc;
    if (rem < cnt) { rh = RH[i]; rw = RW[i]; r = rem / nc; c = rem - (rem / nc) * nc; return; }
    rem -= cnt;
  }
  rh = 4; rw = 4; r = 0; c = 0;
}

__device__ __forceinline__ void win_to_box(int w, float* bb) {
  int rh, rw, r, c;
  win_decode(w, rh, rw, r, c);
  bb[0] = r * 32.f;
  bb[1] = c * 32.f;
  bb[2] = (r + rh) * 32.f - 1.f;
  bb[3] = (c + rw) * 32.f - 1.f;
}

// ---- window scores --------------------------------------------------------
__global__ void winscores_kernel(const float* __restrict__ att, float* __restrict__ s_all,
                                 float* __restrict__ out) {
  int idx = blockIdx.x * blockDim.x + threadIdx.x;
  if (idx >= 16 * 602) return;
  int b = idx / 602, w = idx - b * 602;
  int rh, rw, r, c;
  win_decode(w, rh, rw, r, c);
  const float* a = att + b * 196;
  float s = 0.f;
  for (int dr = 0; dr < rh; ++dr)
    for (int dc = 0; dc < rw; ++dc)
      s += a[(r + dr) * 14 + (c + dc)];
  float v = s / (float)(rh * rw);
  s_all[idx] = v;
  out[OFF_ALL + idx] = v;
}

// ---- NMS: one wave per (batch, group) -------------------------------------
__global__ void nms_kernel(const float* __restrict__ s_all, int* __restrict__ idx_i) {
  const int b = blockIdx.x, g = blockIdx.y;
  const int gs = g ? 361 : 0;
  const int cnt = g ? 241 : 361;
  const int nsel = g ? 3 : 4;
  const int obase = b * 7 + (g ? 4 : 0);
  __shared__ float sc[361];
  __shared__ float bx0[361], bx1[361], bx2[361], bx3[361];
  const int tid = threadIdx.x;
  for (int k = tid; k < cnt; k += 64) {
    sc[k] = s_all[b * 602 + gs + k];
    float bb[4];
    win_to_box(gs + k, bb);
    bx0[k] = bb[0]; bx1[k] = bb[1]; bx2[k] = bb[2]; bx3[k] = bb[3];
  }
  __syncthreads();
  for (int it = 0; it < nsel; ++it) {
    float bv = -INFINITY;
    int bi = 0x7fffffff;
    for (int k = tid; k < cnt; k += 64) {
      float v = sc[k];
      if (v > bv || (v == bv && k < bi)) { bv = v; bi = k; }
    }
#pragma unroll
    for (int off = 32; off > 0; off >>= 1) {
      float ov = __shfl_down(bv, off);
      int oi = __shfl_down(bi, off);
      if (ov > bv || (ov == bv && oi < bi)) { bv = ov; bi = oi; }
    }
    bi = __shfl(bi, 0);
    if (tid == 0) idx_i[obase + it] = gs + bi;
    float X0 = bx0[bi], X1 = bx1[bi], X2 = bx2[bi], X3 = bx3[bi];
    float a1 = (X2 - X0 + 1.f) * (X3 - X1 + 1.f);
    __syncthreads();
    for (int k = tid; k < cnt; k += 64) {
      float x0 = fmaxf(X0, bx0[k]);
      float y0 = fmaxf(X1, bx1[k]);
      float x1 = fminf(X2, bx2[k]);
      float y1 = fminf(X3, bx3[k]);
      float inter = fmaxf(x1 - x0 + 1.f, 0.f) * fmaxf(y1 - y0 + 1.f, 0.f);
      float a2 = (bx2[k] - bx0[k] + 1.f) * (bx3[k] - bx1[k] + 1.f);
      float iou = inter / (a1 + a2 - inter);
      if (iou > 0.25f) sc[k] = -INFINITY;
    }
    if (tid == 0) sc[bi] = -INFINITY;
    __syncthreads();
  }
}

// ---- gather ---------------------------------------------------------------
__global__ void gather_kernel(const int* __restrict__ idx_i, const float* __restrict__ s_all,
                              float* __restrict__ boxes, float* __restrict__ out) {
  int t = blockIdx.x * blockDim.x + threadIdx.x;
  if (t >= 112) return;
  int b = t / 7;
  int w = idx_i[t];
  out[OFF_IDX + t] = (float)w;
  out[OFF_WSC + t] = s_all[b * 602 + w];
  float bb[4];
  win_to_box(w, bb);
#pragma unroll
  for (int k = 0; k < 4; ++k) {
    boxes[t * 4 + k] = bb[k];
    out[OFF_CRD + t * 4 + k] = bb[k];
  }
}

// ---- bilinear crop-resize 448 -> 112 --------------------------------------
__global__ void crop_resize_kernel(const float* __restrict__ x, const float* __restrict__ boxes,
                                   float* __restrict__ wimgs) {
  int idx = blockIdx.x * blockDim.x + threadIdx.x;
  const int total = 112 * 3 * 112 * 112;
  if (idx >= total) return;
  int j = idx % 112;
  int i = (idx / 112) % 112;
  int ch = (idx / (112 * 112)) % 3;
  int bp = idx / (3 * 112 * 112);
  int b = bp / 7;
  const float* bx = boxes + bp * 4;
  float t_i = (float)i / 111.0f;
  float t_j = (float)j / 111.0f;
  float rs = bx[0] + (bx[2] - bx[0]) * t_i;
  float cs = bx[1] + (bx[3] - bx[1]) * t_j;
  float r0f = floorf(rs), c0f = floorf(cs);
  float wr = rs - r0f, wc = cs - c0f;
  int r0 = (int)r0f, c0 = (int)c0f;
  int r1 = min(r0 + 1, 447), c1 = min(c0 + 1, 447);
  const float* img = x + ((size_t)b * 3 + ch) * 448 * 448;
  float v00 = img[r0 * 448 + c0], v01 = img[r0 * 448 + c1];
  float v10 = img[r1 * 448 + c0], v11 = img[r1 * 448 + c1];
  float top = (1.f - wc) * v00 + wc * v01;
  float bot = (1.f - wc) * v10 + wc * v11;
  wimgs[idx] = (1.f - wr) * top + wr * bot;
}

// ---- zero fill ------------------------------------------------------------
__global__ void zerofill_kernel(float* __restrict__ p, int n) {
  int idx = blockIdx.x * blockDim.x + threadIdx.x;
  if (idx < n) p[idx] = 0.f;
}

// ======================= tile conv (all layers) =============================
// PIXT=4 pixels x 8 co per thread; weights in LDS [ci][k][co] (b128 broadcast),
// staged in 64-ci chunks. Output strides (oplane,orow,ooff) allow writing into
// padded layouts. Proven structure (VGPR 68, no spill).
__global__ __launch_bounds__(256, 2) void conv_t8_kernel(
    const float* __restrict__ in, const float* __restrict__ wt,
    const float* __restrict__ bias, float* __restrict__ out,
    int N, int Cin, int Hin, int Win, int Hout, int Wout, int pad,
    int oplane, int orow, int ooff) {
  const int Cout = gridDim.x * 8;
  const int co0 = blockIdx.x * 8;
  const int nTw = (Wout + 3) >> 2;
  const int tiles = N * Hout * nTw;
  const int lin = blockIdx.y * 256 + threadIdx.x;
  const bool active = lin < tiles;
  int tw = 0, oh = 0, n = 0;
  if (active) {
    tw = lin % nTw;
    int t2 = lin / nTw;
    oh = t2 % Hout;
    n = t2 / Hout;
  }
  const int owb = tw * 4;
  const int ih0 = 2 * oh - pad;
  const int iw0 = 2 * owb - pad;
  const size_t inplane = (size_t)Hin * Win;
  const float* nbase = in + (size_t)n * Cin * inplane;
  const bool r2ok = (ih0 + 2 < Hin);
  const bool c8ok = (iw0 + 8 < Win);
  const bool fullt = (owb + 3 < Wout);
  const bool fast = active && (ih0 >= 0) && (iw0 >= 0) && (iw0 + 7 < Win) && fullt;
  const bool vload = ((Win & 3) == 0) && (pad == 0);

  float acc[8][4];
#pragma unroll
  for (int j = 0; j < 8; ++j)
#pragma unroll
    for (int p = 0; p < 4; ++p) acc[j][p] = 0.f;

  __shared__ float w_lds[64 * 9 * 8];

  const int nchunk = (Cin + 63) >> 6;
  for (int ch = 0; ch < nchunk; ++ch) {
    const int ci0 = ch << 6;
    const int cich = min(64, Cin - ci0);
    const int nel = cich * 9;
    for (int t = threadIdx.x; t < nel * 8; t += 256) {
      int co = t / nel;
      int rem = t - co * nel;
      w_lds[rem * 8 + co] = wt[(size_t)(co0 + co) * Cin * 9 + (size_t)ci0 * 9 + rem];
    }
    __syncthreads();
    if (fast) {
      const float* pb = nbase + (size_t)ci0 * inplane + (size_t)ih0 * Win + iw0;
      for (int ci = 0; ci < cich; ++ci) {
        const float* p0 = pb + (size_t)ci * inplane;
        const float* p1 = p0 + Win;
        const float* p2 = p1 + Win;
        float rr[3][9];
        if (vload) {
          float4 a0 = *(const float4*)p0, b0 = *(const float4*)(p0 + 4);
          rr[0][0] = a0.x; rr[0][1] = a0.y; rr[0][2] = a0.z; rr[0][3] = a0.w;
          rr[0][4] = b0.x; rr[0][5] = b0.y; rr[0][6] = b0.z; rr[0][7] = b0.w;
          float4 a1 = *(const float4*)p1, b1 = *(const float4*)(p1 + 4);
          rr[1][0] = a1.x; rr[1][1] = a1.y; rr[1][2] = a1.z; rr[1][3] = a1.w;
          rr[1][4] = b1.x; rr[1][5] = b1.y; rr[1][6] = b1.z; rr[1][7] = b1.w;
          if (r2ok) {
            float4 a2 = *(const float4*)p2, b2 = *(const float4*)(p2 + 4);
            rr[2][0] = a2.x; rr[2][1] = a2.y; rr[2][2] = a2.z; rr[2][3] = a2.w;
            rr[2][4] = b2.x; rr[2][5] = b2.y; rr[2][6] = b2.z; rr[2][7] = b2.w;
          } else {
#pragma unroll
            for (int cc = 0; cc < 8; ++cc) rr[2][cc] = 0.f;
          }
        } else {
#pragma unroll
          for (int cc = 0; cc < 8; ++cc) rr[0][cc] = p0[cc];
#pragma unroll
          for (int cc = 0; cc < 8; ++cc) rr[1][cc] = p1[cc];
          if (r2ok) {
#pragma unroll
            for (int cc = 0; cc < 8; ++cc) rr[2][cc] = p2[cc];
          } else {
#pragma unroll
            for (int cc = 0; cc < 8; ++cc) rr[2][cc] = 0.f;
          }
        }
        rr[0][8] = c8ok ? p0[8] : 0.f;
        rr[1][8] = c8ok ? p1[8] : 0.f;
        rr[2][8] = (c8ok && r2ok) ? p2[8] : 0.f;
        const int b9 = ci * 9;
#pragma unroll
        for (int kh = 0; kh < 3; ++kh) {
#pragma unroll
          for (int kw = 0; kw < 3; ++kw) {
            const float* wp = &w_lds[(b9 + kh * 3 + kw) * 8];
            float4 wlo = *(const float4*)wp;
            float4 whi = *(const float4*)(wp + 4);
#pragma unroll
            for (int px = 0; px < 4; ++px) {
              float v = rr[kh][kw + 2 * px];
              acc[0][px] = fmaf(v, wlo.x, acc[0][px]);
              acc[1][px] = fmaf(v, wlo.y, acc[1][px]);
              acc[2][px] = fmaf(v, wlo.z, acc[2][px]);
              acc[3][px] = fmaf(v, wlo.w, acc[3][px]);
              acc[4][px] = fmaf(v, whi.x, acc[4][px]);
              acc[5][px] = fmaf(v, whi.y, acc[5][px]);
              acc[6][px] = fmaf(v, whi.z, acc[6][px]);
              acc[7][px] = fmaf(v, whi.w, acc[7][px]);
            }
          }
        }
      }
    } else if (active) {
      for (int ci = 0; ci < cich; ++ci) {
        const float* p = nbase + (size_t)(ci0 + ci) * inplane;
        const int b9 = ci * 9;
#pragma unroll
        for (int px = 0; px < 4; ++px) {
          int ow = owb + px;
          if (ow >= Wout) continue;
          int iwp = 2 * ow - pad;
#pragma unroll
          for (int kh = 0; kh < 3; ++kh) {
            int ih = ih0 + kh;
            if ((unsigned)ih >= (unsigned)Hin) continue;
#pragma unroll
            for (int kw = 0; kw < 3; ++kw) {
              int iw = iwp + kw;
              if ((unsigned)iw >= (unsigned)Win) continue;
              float v = p[(size_t)ih * Win + iw];
              const float* wp = &w_lds[(b9 + kh * 3 + kw) * 8];
#pragma unroll
              for (int j = 0; j < 8; ++j) acc[j][px] = fmaf(v, wp[j], acc[j][px]);
            }
          }
        }
      }
    }
    __syncthreads();
  }
  if (!active) return;
  float* ob = out + ((size_t)n * Cout + co0) * oplane + (size_t)oh * orow + owb + ooff;
#pragma unroll
  for (int j = 0; j < 8; ++j) {
    float bj = bias[co0 + j];
    float* oj = ob + (size_t)j * oplane;
    if (((Wout & 3) == 0) && fullt) {
      float4 v;
      v.x = fmaxf(acc[j][0] + bj, 0.f);
      v.y = fmaxf(acc[j][1] + bj, 0.f);
      v.z = fmaxf(acc[j][2] + bj, 0.f);
      v.w = fmaxf(acc[j][3] + bj, 0.f);
      *(float4*)oj = v;
    } else {
#pragma unroll
      for (int p = 0; p < 4; ++p)
        if (owb + p < Wout) oj[p] = fmaxf(acc[j][p] + bj, 0.f);
    }
  }
}

// ---- mean pool ------------------------------------------------------------
__global__ void avgpool_kernel(const float* __restrict__ feat, float* __restrict__ pooled,
                               int M, int C, int S) {
  int idx = blockIdx.x * blockDim.x + threadIdx.x;
  if (idx >= M * C) return;
  const float* p = feat + (size_t)idx * S;
  float s = 0.f;
  for (int i = 0; i < S; ++i) s += p[i];
  pooled[idx] = s / (float)S;
}

// ---- head GEMM ------------------------------------------------------------
__global__ void head_kernel(const float* __restrict__ pooled, const float* __restrict__ hw,
                            const float* __restrict__ hb, float* __restrict__ outp, int M) {
  int idx = blockIdx.x * blockDim.x + threadIdx.x;
  if (idx >= M * 200) return;
  int m = idx / 200, c = idx - m * 200;
  float acc = hb[c];
  const float* pm = pooled + m * 512;
  for (int k = 0; k < 512; ++k) acc = fmaf(pm[k], hw[k * 200 + c], acc);
  outp[idx] = acc;
}

// ---------------------------------------------------------------------------
static void launch_A(const float* in, const float* wt, const float* bias, float* out,
                     int N, int Cin, int Hin, int Hout, int Cout, hipStream_t s) {
  int nTw = (Hout + 3) >> 2;
  int tiles = N * Hout * nTw;
  dim3 grid(Cout / 8, cdiv(tiles, 256));
  conv_t8_kernel<<<grid, 256, 0, s>>>(in, wt, bias, out, N, Cin, Hin, Hin, Hout, Hout, 0,
                                      Hout * Hout, Hout, 0);
}

extern "C" void kernel_launch(void* const* d_in, const int* in_sizes, int n_in,
                              void* d_out, int out_size, void* d_ws, size_t ws_size,
                              hipStream_t stream) {
  const float* x = (const float*)d_in[0];
  const float* att = (const float*)d_in[1];
  const float* W[5] = {(const float*)d_in[2], (const float*)d_in[4], (const float*)d_in[6],
                       (const float*)d_in[8], (const float*)d_in[10]};
  const float* Bv[5] = {(const float*)d_in[3], (const float*)d_in[5], (const float*)d_in[7],
                        (const float*)d_in[9], (const float*)d_in[11]};
  const float* head_w = (const float*)d_in[12];
  const float* head_b = (const float*)d_in[13];
  float* out = (float*)d_out;
  float* ws = (float*)d_ws;

  // workspace layout (floats), ~130MB (round-3/7 proven)
  size_t o = 0;
  float* s_all = ws + o;  o += 16 * 602;
  int* idx_i = (int*)(ws + o); o += 112;
  float* boxes = ws + o;  o += 112 * 4;
  float* wimgs = ws + o;  o += (size_t)112 * 3 * 112 * 112;
  float* featB = ws + o;  o += (size_t)16 * 512 * 196;   // big L4 out; reused as crop L4 out
  float* featC = featB;                                   // alias (featB dead after big head)
  float* pooled = ws + o; o += (size_t)112 * 512;
  float* featL3 = ws + o; o += (size_t)16 * 512 * 784;   // big L3 out; reused padded crop L3 out
  float* bufA = ws + o;   o += (size_t)4 * 64 * 224 * 224;
  float* bufB = ws + o;   o += (size_t)4 * 128 * 112 * 112;

  // ---- proposal path ----
  winscores_kernel<<<cdiv(16 * 602, BS), BS, 0, stream>>>(att, s_all, out);
  nms_kernel<<<dim3(16, 2), 64, 0, stream>>>(s_all, idx_i);
  gather_kernel<<<1, 128, 0, stream>>>(idx_i, s_all, boxes, out);
  crop_resize_kernel<<<cdiv(112 * 3 * 112 * 112, BS), BS, 0, stream>>>(x, boxes, wimgs);

  // ---- big encoder: L0-L3 in 4-image chunks, L4 over all 16 ----
  for (int chunk = 0; chunk < 4; ++chunk) {
    int n0 = chunk * 4;
    const float* in0 = x + (size_t)n0 * 3 * 448 * 448;
    launch_A(in0, W[0], Bv[0], bufA, 4, 3, 448, 224, 64, stream);           // (8,196)
    launch_A(bufA, W[1], Bv[1], bufB, 4, 64, 224, 112, 128, stream);        // (16,49)
    launch_A(bufB, W[2], Bv[2], bufA, 4, 128, 112, 56, 256, stream);        // (32,13)
    launch_A(bufA, W[3], Bv[3], featL3 + (size_t)n0 * 512 * 784, 4, 256, 56, 28, 512,
             stream);                                                        // (64,4)
  }
  launch_A(featL3, W[4], Bv[4], featB, 16, 512, 28, 14, 512, stream);       // (64,4)
  avgpool_kernel<<<cdiv(16 * 512, BS), BS, 0, stream>>>(featB, pooled, 16, 512, 196);
  head_kernel<<<cdiv(16 * 200, BS), BS, 0, stream>>>(pooled, head_w, head_b, out + OFF_LAB, 16);

  // zero the padded crop-L3 buffer (9x9 planes) -- after big L4 consumed featL3
  zerofill_kernel<<<cdiv(112 * 512 * 81, BS), BS, 0, stream>>>(featL3, 112 * 512 * 81);

  // ---- crop encoder: L0-L3 in 56-crop chunks, L4 over all 112 ----
  for (int chunk = 0; chunk < 2; ++chunk) {
    int c0 = chunk * 56;
    const float* in0 = wimgs + (size_t)c0 * 3 * 112 * 112;
    launch_A(in0, W[0], Bv[0], bufA, 56, 3, 112, 56, 64, stream);           // (8,172)
    launch_A(bufA, W[1], Bv[1], bufB, 56, 64, 56, 28, 128, stream);         // (16,43)
    launch_A(bufB, W[2], Bv[2], bufA, 56, 128, 28, 14, 256, stream);        // (32,13)
    {  // crop L3: 14->7, write into padded 9x9 planes at (oh+1, ow+1)
      int tiles = 56 * 7 * 2;
      dim3 grid(64, cdiv(tiles, 256));
      conv_t8_kernel<<<grid, 256, 0, stream>>>(bufA, W[3], Bv[3],
                                               featL3 + (size_t)c0 * 512 * 81, 56, 256, 14, 14,
                                               7, 7, 0, 81, 9, 10);
    }
  }
  {  // crop L4: read padded 9x9 planes, "pad=0" -> all tiles fast-path
    int tiles = 112 * 4 * 1;
    dim3 grid(64, cdiv(tiles, 256));
    conv_t8_kernel<<<grid, 256, 0, stream>>>(featL3, W[4], Bv[4], featC, 112, 512, 9, 9, 4, 4, 0,
                                             16, 4, 0);
  }
  avgpool_kernel<<<cdiv(112 * 512, BS), BS, 0, stream>>>(featC, pooled, 112, 512, 16);
  head_kernel<<<cdiv(112 * 200, BS), BS, 0, stream>>>(pooled, head_w, head_b, out + OFF_LOG, 112);
}

// Round 9
// 10221.104 us; speedup vs baseline: 1.2135x; 1.2135x over previous
//
#include <hip/hip_runtime.h>
#include <hip/hip_bf16.h>
#include <math.h>

// ---------------------------------------------------------------------------
// Classifier_with_Augmentation: NTS-Net-style pipeline.
//  outputs (flat float32 in d_out):
//   labels 16x200 @0 | win_scores 16x7 @3200 | win_logits 112x200 @3312
//   indices 16x7 @25712 | all_scores 16x602 @25824 | coordinates 16x7x4 @35456
// ---------------------------------------------------------------------------

#define OFF_LAB 0
#define OFF_WSC 3200
#define OFF_LOG 3312
#define OFF_IDX 25712
#define OFF_ALL 25824
#define OFF_CRD 35456

#define BS 256

static inline int cdiv(int a, int b) { return (a + b - 1) / b; }

// ---- window geometry ------------------------------------------------------
__device__ __forceinline__ void win_decode(int w, int& rh, int& rw, int& r, int& c) {
  const int RH[6] = {4, 3, 5, 6, 5, 7};
  const int RW[6] = {4, 5, 3, 6, 7, 5};
  int rem = w;
#pragma unroll
  for (int i = 0; i < 6; ++i) {
    int nc = 15 - RW[i];
    int cnt = (15 - RH[i]) * nc;
    if (rem < cnt) { rh = RH[i]; rw = RW[i]; r = rem / nc; c = rem - (rem / nc) * nc; return; }
    rem -= cnt;
  }
  rh = 4; rw = 4; r = 0; c = 0;
}

__device__ __forceinline__ void win_to_box(int w, float* bb) {
  int rh, rw, r, c;
  win_decode(w, rh, rw, r, c);
  bb[0] = r * 32.f;
  bb[1] = c * 32.f;
  bb[2] = (r + rh) * 32.f - 1.f;
  bb[3] = (c + rw) * 32.f - 1.f;
}

// ---- window scores --------------------------------------------------------
__global__ void winscores_kernel(const float* __restrict__ att, float* __restrict__ s_all,
                                 float* __restrict__ out) {
  int idx = blockIdx.x * blockDim.x + threadIdx.x;
  if (idx >= 16 * 602) return;
  int b = idx / 602, w = idx - b * 602;
  int rh, rw, r, c;
  win_decode(w, rh, rw, r, c);
  const float* a = att + b * 196;
  float s = 0.f;
  for (int dr = 0; dr < rh; ++dr)
    for (int dc = 0; dc < rw; ++dc)
      s += a[(r + dr) * 14 + (c + dc)];
  float v = s / (float)(rh * rw);
  s_all[idx] = v;
  out[OFF_ALL + idx] = v;
}

// ---- NMS: one wave per (batch, group) -------------------------------------
__global__ void nms_kernel(const float* __restrict__ s_all, int* __restrict__ idx_i) {
  const int b = blockIdx.x, g = blockIdx.y;
  const int gs = g ? 361 : 0;
  const int cnt = g ? 241 : 361;
  const int nsel = g ? 3 : 4;
  const int obase = b * 7 + (g ? 4 : 0);
  __shared__ float sc[361];
  __shared__ float bx0[361], bx1[361], bx2[361], bx3[361];
  const int tid = threadIdx.x;
  for (int k = tid; k < cnt; k += 64) {
    sc[k] = s_all[b * 602 + gs + k];
    float bb[4];
    win_to_box(gs + k, bb);
    bx0[k] = bb[0]; bx1[k] = bb[1]; bx2[k] = bb[2]; bx3[k] = bb[3];
  }
  __syncthreads();
  for (int it = 0; it < nsel; ++it) {
    float bv = -INFINITY;
    int bi = 0x7fffffff;
    for (int k = tid; k < cnt; k += 64) {
      float v = sc[k];
      if (v > bv || (v == bv && k < bi)) { bv = v; bi = k; }
    }
#pragma unroll
    for (int off = 32; off > 0; off >>= 1) {
      float ov = __shfl_down(bv, off);
      int oi = __shfl_down(bi, off);
      if (ov > bv || (ov == bv && oi < bi)) { bv = ov; bi = oi; }
    }
    bi = __shfl(bi, 0);
    if (tid == 0) idx_i[obase + it] = gs + bi;
    float X0 = bx0[bi], X1 = bx1[bi], X2 = bx2[bi], X3 = bx3[bi];
    float a1 = (X2 - X0 + 1.f) * (X3 - X1 + 1.f);
    __syncthreads();
    for (int k = tid; k < cnt; k += 64) {
      float x0 = fmaxf(X0, bx0[k]);
      float y0 = fmaxf(X1, bx1[k]);
      float x1 = fminf(X2, bx2[k]);
      float y1 = fminf(X3, bx3[k]);
      float inter = fmaxf(x1 - x0 + 1.f, 0.f) * fmaxf(y1 - y0 + 1.f, 0.f);
      float a2 = (bx2[k] - bx0[k] + 1.f) * (bx3[k] - bx1[k] + 1.f);
      float iou = inter / (a1 + a2 - inter);
      if (iou > 0.25f) sc[k] = -INFINITY;
    }
    if (tid == 0) sc[bi] = -INFINITY;
    __syncthreads();
  }
}

// ---- gather ---------------------------------------------------------------
__global__ void gather_kernel(const int* __restrict__ idx_i, const float* __restrict__ s_all,
                              float* __restrict__ boxes, float* __restrict__ out) {
  int t = blockIdx.x * blockDim.x + threadIdx.x;
  if (t >= 112) return;
  int b = t / 7;
  int w = idx_i[t];
  out[OFF_IDX + t] = (float)w;
  out[OFF_WSC + t] = s_all[b * 602 + w];
  float bb[4];
  win_to_box(w, bb);
#pragma unroll
  for (int k = 0; k < 4; ++k) {
    boxes[t * 4 + k] = bb[k];
    out[OFF_CRD + t * 4 + k] = bb[k];
  }
}

// ---- bilinear crop-resize 448 -> 112 --------------------------------------
__global__ void crop_resize_kernel(const float* __restrict__ x, const float* __restrict__ boxes,
                                   float* __restrict__ wimgs) {
  int idx = blockIdx.x * blockDim.x + threadIdx.x;
  const int total = 112 * 3 * 112 * 112;
  if (idx >= total) return;
  int j = idx % 112;
  int i = (idx / 112) % 112;
  int ch = (idx / (112 * 112)) % 3;
  int bp = idx / (3 * 112 * 112);
  int b = bp / 7;
  const float* bx = boxes + bp * 4;
  float t_i = (float)i / 111.0f;
  float t_j = (float)j / 111.0f;
  float rs = bx[0] + (bx[2] - bx[0]) * t_i;
  float cs = bx[1] + (bx[3] - bx[1]) * t_j;
  float r0f = floorf(rs), c0f = floorf(cs);
  float wr = rs - r0f, wc = cs - c0f;
  int r0 = (int)r0f, c0 = (int)c0f;
  int r1 = min(r0 + 1, 447), c1 = min(c0 + 1, 447);
  const float* img = x + ((size_t)b * 3 + ch) * 448 * 448;
  float v00 = img[r0 * 448 + c0], v01 = img[r0 * 448 + c1];
  float v10 = img[r1 * 448 + c0], v11 = img[r1 * 448 + c1];
  float top = (1.f - wc) * v00 + wc * v01;
  float bot = (1.f - wc) * v10 + wc * v11;
  wimgs[idx] = (1.f - wr) * top + wr * bot;
}

// ---- zero fill ------------------------------------------------------------
__global__ void zerofill_kernel(float* __restrict__ p, int n) {
  int idx = blockIdx.x * blockDim.x + threadIdx.x;
  if (idx < n) p[idx] = 0.f;
}

// ======================= tile conv, split-K over blockIdx.z =================
// PIXT=4 pixels x 8 co per thread; weights in LDS [ci][k][co] (b128 broadcast).
// Each block handles ONE 64-ci chunk (ci0 = blockIdx.z*64).
//  gridDim.z == 1 : direct write (bias+relu), strided by oplane/orow/ooff.
//  gridDim.z  > 1 : raw partial sums to out + z*N*Cout*HW (compact layout);
//                   reduce_kernel sums z-slices + bias + relu.
__global__ __launch_bounds__(256, 2) void conv_t8_kernel(
    const float* __restrict__ in, const float* __restrict__ wt,
    const float* __restrict__ bias, float* __restrict__ out,
    int N, int Cin, int Hin, int Win, int Hout, int Wout, int pad,
    int oplane, int orow, int ooff) {
  const int Cout = gridDim.x * 8;
  const int co0 = blockIdx.x * 8;
  const int nTw = (Wout + 3) >> 2;
  const int tiles = N * Hout * nTw;
  const int lin = blockIdx.y * 256 + threadIdx.x;
  const bool active = lin < tiles;
  int tw = 0, oh = 0, n = 0;
  if (active) {
    tw = lin % nTw;
    int t2 = lin / nTw;
    oh = t2 % Hout;
    n = t2 / Hout;
  }
  const int owb = tw * 4;
  const int ih0 = 2 * oh - pad;
  const int iw0 = 2 * owb - pad;
  const size_t inplane = (size_t)Hin * Win;
  const float* nbase = in + (size_t)n * Cin * inplane;
  const bool r2ok = (ih0 + 2 < Hin);
  const bool c8ok = (iw0 + 8 < Win);
  const bool fullt = (owb + 3 < Wout);
  const bool fast = active && (ih0 >= 0) && (iw0 >= 0) && (iw0 + 7 < Win) && fullt;
  const bool vload = ((Win & 3) == 0) && (pad == 0);

  float acc[8][4];
#pragma unroll
  for (int j = 0; j < 8; ++j)
#pragma unroll
    for (int p = 0; p < 4; ++p) acc[j][p] = 0.f;

  __shared__ float w_lds[64 * 9 * 8];

  const int ci0 = blockIdx.z << 6;
  const int cich = min(64, Cin - ci0);
  const int nel = cich * 9;
  for (int t = threadIdx.x; t < nel * 8; t += 256) {
    int co = t / nel;
    int rem = t - co * nel;
    w_lds[rem * 8 + co] = wt[(size_t)(co0 + co) * Cin * 9 + (size_t)ci0 * 9 + rem];
  }
  __syncthreads();
  if (fast) {
    const float* pb = nbase + (size_t)ci0 * inplane + (size_t)ih0 * Win + iw0;
    for (int ci = 0; ci < cich; ++ci) {
      const float* p0 = pb + (size_t)ci * inplane;
      const float* p1 = p0 + Win;
      const float* p2 = p1 + Win;
      float rr[3][9];
      if (vload) {
        float4 a0 = *(const float4*)p0, b0 = *(const float4*)(p0 + 4);
        rr[0][0] = a0.x; rr[0][1] = a0.y; rr[0][2] = a0.z; rr[0][3] = a0.w;
        rr[0][4] = b0.x; rr[0][5] = b0.y; rr[0][6] = b0.z; rr[0][7] = b0.w;
        float4 a1 = *(const float4*)p1, b1 = *(const float4*)(p1 + 4);
        rr[1][0] = a1.x; rr[1][1] = a1.y; rr[1][2] = a1.z; rr[1][3] = a1.w;
        rr[1][4] = b1.x; rr[1][5] = b1.y; rr[1][6] = b1.z; rr[1][7] = b1.w;
        if (r2ok) {
          float4 a2 = *(const float4*)p2, b2 = *(const float4*)(p2 + 4);
          rr[2][0] = a2.x; rr[2][1] = a2.y; rr[2][2] = a2.z; rr[2][3] = a2.w;
          rr[2][4] = b2.x; rr[2][5] = b2.y; rr[2][6] = b2.z; rr[2][7] = b2.w;
        } else {
#pragma unroll
          for (int cc = 0; cc < 8; ++cc) rr[2][cc] = 0.f;
        }
      } else {
#pragma unroll
        for (int cc = 0; cc < 8; ++cc) rr[0][cc] = p0[cc];
#pragma unroll
        for (int cc = 0; cc < 8; ++cc) rr[1][cc] = p1[cc];
        if (r2ok) {
#pragma unroll
          for (int cc = 0; cc < 8; ++cc) rr[2][cc] = p2[cc];
        } else {
#pragma unroll
          for (int cc = 0; cc < 8; ++cc) rr[2][cc] = 0.f;
        }
      }
      rr[0][8] = c8ok ? p0[8] : 0.f;
      rr[1][8] = c8ok ? p1[8] : 0.f;
      rr[2][8] = (c8ok && r2ok) ? p2[8] : 0.f;
      const int b9 = ci * 9;
#pragma unroll
      for (int kh = 0; kh < 3; ++kh) {
#pragma unroll
        for (int kw = 0; kw < 3; ++kw) {
          const float* wp = &w_lds[(b9 + kh * 3 + kw) * 8];
          float4 wlo = *(const float4*)wp;
          float4 whi = *(const float4*)(wp + 4);
#pragma unroll
          for (int px = 0; px < 4; ++px) {
            float v = rr[kh][kw + 2 * px];
            acc[0][px] = fmaf(v, wlo.x, acc[0][px]);
            acc[1][px] = fmaf(v, wlo.y, acc[1][px]);
            acc[2][px] = fmaf(v, wlo.z, acc[2][px]);
            acc[3][px] = fmaf(v, wlo.w, acc[3][px]);
            acc[4][px] = fmaf(v, whi.x, acc[4][px]);
            acc[5][px] = fmaf(v, whi.y, acc[5][px]);
            acc[6][px] = fmaf(v, whi.z, acc[6][px]);
            acc[7][px] = fmaf(v, whi.w, acc[7][px]);
          }
        }
      }
    }
  } else if (active) {
    for (int ci = 0; ci < cich; ++ci) {
      const float* p = nbase + (size_t)(ci0 + ci) * inplane;
      const int b9 = ci * 9;
#pragma unroll
      for (int px = 0; px < 4; ++px) {
        int ow = owb + px;
        if (ow >= Wout) continue;
        int iwp = 2 * ow - pad;
#pragma unroll
        for (int kh = 0; kh < 3; ++kh) {
          int ih = ih0 + kh;
          if ((unsigned)ih >= (unsigned)Hin) continue;
#pragma unroll
          for (int kw = 0; kw < 3; ++kw) {
            int iw = iwp + kw;
            if ((unsigned)iw >= (unsigned)Win) continue;
            float v = p[(size_t)ih * Win + iw];
            const float* wp = &w_lds[(b9 + kh * 3 + kw) * 8];
#pragma unroll
            for (int j = 0; j < 8; ++j) acc[j][px] = fmaf(v, wp[j], acc[j][px]);
          }
        }
      }
    }
  }
  if (!active) return;
  const int HW = Hout * Wout;
  if (gridDim.z == 1) {
    float* ob = out + ((size_t)n * Cout + co0) * oplane + (size_t)oh * orow + owb + ooff;
#pragma unroll
    for (int j = 0; j < 8; ++j) {
      float bj = bias[co0 + j];
      float* oj = ob + (size_t)j * oplane;
      if (((Wout & 3) == 0) && fullt) {
        float4 v;
        v.x = fmaxf(acc[j][0] + bj, 0.f);
        v.y = fmaxf(acc[j][1] + bj, 0.f);
        v.z = fmaxf(acc[j][2] + bj, 0.f);
        v.w = fmaxf(acc[j][3] + bj, 0.f);
        *(float4*)oj = v;
      } else {
#pragma unroll
        for (int p = 0; p < 4; ++p)
          if (owb + p < Wout) oj[p] = fmaxf(acc[j][p] + bj, 0.f);
      }
    }
  } else {
    const size_t Nout = (size_t)N * Cout * HW;
    float* ob = out + (size_t)blockIdx.z * Nout + ((size_t)n * Cout + co0) * HW +
                (size_t)oh * Wout + owb;
#pragma unroll
    for (int j = 0; j < 8; ++j) {
      float* oj = ob + (size_t)j * HW;
      if (((Wout & 3) == 0) && fullt) {
        float4 v;
        v.x = acc[j][0]; v.y = acc[j][1]; v.z = acc[j][2]; v.w = acc[j][3];
        *(float4*)oj = v;
      } else {
#pragma unroll
        for (int p = 0; p < 4; ++p)
          if (owb + p < Wout) oj[p] = acc[j][p];
      }
    }
  }
}

// ---- reduce partial z-slices + bias + relu, write (possibly padded) -------
__global__ void reduce_kernel(const float* __restrict__ part, const float* __restrict__ bias,
                              float* __restrict__ out, int Nout, int HW, int Cout, int nz,
                              int oplane, int orow, int ooff, int Wout) {
  int idx = blockIdx.x * blockDim.x + threadIdx.x;
  if (idx >= Nout) return;
  float s = 0.f;
  for (int z = 0; z < nz; ++z) s += part[(size_t)z * Nout + idx];
  int nco = idx / HW, pix = idx - nco * HW;
  int co = nco % Cout;
  s = fmaxf(s + bias[co], 0.f);
  int oh = pix / Wout, ow = pix - oh * Wout;
  out[(size_t)nco * oplane + (size_t)oh * orow + ow + ooff] = s;
}

// ---- mean pool ------------------------------------------------------------
__global__ void avgpool_kernel(const float* __restrict__ feat, float* __restrict__ pooled,
                               int M, int C, int S) {
  int idx = blockIdx.x * blockDim.x + threadIdx.x;
  if (idx >= M * C) return;
  const float* p = feat + (size_t)idx * S;
  float s = 0.f;
  for (int i = 0; i < S; ++i) s += p[i];
  pooled[idx] = s / (float)S;
}

// ---- head GEMM ------------------------------------------------------------
__global__ void head_kernel(const float* __restrict__ pooled, const float* __restrict__ hw,
                            const float* __restrict__ hb, float* __restrict__ outp, int M) {
  int idx = blockIdx.x * blockDim.x + threadIdx.x;
  if (idx >= M * 200) return;
  int m = idx / 200, c = idx - m * 200;
  float acc = hb[c];
  const float* pm = pooled + m * 512;
  for (int k = 0; k < 512; ++k) acc = fmaf(pm[k], hw[k * 200 + c], acc);
  outp[idx] = acc;
}

// ---------------------------------------------------------------------------
// conv_layer: direct if Cin<=64, else split-K (partials in pbuf) + reduce.
static void conv_layer(const float* in, const float* wt, const float* bv, float* dst, float* pbuf,
                       int N, int Cin, int Hin, int Hout, int Cout, int pad,
                       int oplane, int orow, int ooff, hipStream_t s) {
  int Wout = Hout;
  int nTw = (Hout + 3) >> 2;
  int tiles = N * Hout * nTw;
  int nz = (Cin + 63) >> 6;
  int HW = Hout * Wout;
  if (nz == 1) {
    dim3 grid(Cout / 8, cdiv(tiles, 256), 1);
    conv_t8_kernel<<<grid, 256, 0, s>>>(in, wt, bv, dst, N, Cin, Hin, Hin, Hout, Wout, pad,
                                        oplane, orow, ooff);
  } else {
    dim3 grid(Cout / 8, cdiv(tiles, 256), nz);
    conv_t8_kernel<<<grid, 256, 0, s>>>(in, wt, bv, pbuf, N, Cin, Hin, Hin, Hout, Wout, pad,
                                        HW, Wout, 0);
    int Nout = N * Cout * HW;
    reduce_kernel<<<cdiv(Nout, 256), 256, 0, s>>>(pbuf, bv, dst, Nout, HW, Cout, nz,
                                                  oplane, orow, ooff, Wout);
  }
}

extern "C" void kernel_launch(void* const* d_in, const int* in_sizes, int n_in,
                              void* d_out, int out_size, void* d_ws, size_t ws_size,
                              hipStream_t stream) {
  const float* x = (const float*)d_in[0];
  const float* att = (const float*)d_in[1];
  const float* W[5] = {(const float*)d_in[2], (const float*)d_in[4], (const float*)d_in[6],
                       (const float*)d_in[8], (const float*)d_in[10]};
  const float* Bv[5] = {(const float*)d_in[3], (const float*)d_in[5], (const float*)d_in[7],
                        (const float*)d_in[9], (const float*)d_in[11]};
  const float* head_w = (const float*)d_in[12];
  const float* head_b = (const float*)d_in[13];
  float* out = (float*)d_out;
  float* ws = (float*)d_ws;

  // workspace layout (floats), ~130MB (round-8 proven)
  size_t o = 0;
  float* s_all = ws + o;  o += 16 * 602;
  int* idx_i = (int*)(ws + o); o += 112;
  float* boxes = ws + o;  o += 112 * 4;
  float* wimgs = ws + o;  o += (size_t)112 * 3 * 112 * 112;
  float* featB = ws + o;  o += (size_t)16 * 512 * 196;   // big L4 out; reused as crop L4 out
  float* featC = featB;
  float* pooled = ws + o; o += (size_t)112 * 512;
  float* featL3 = ws + o; o += (size_t)16 * 512 * 784;   // big L3 out; reused padded crop L3 out
  float* bufA = ws + o;   o += (size_t)4 * 64 * 224 * 224;   // 12,845,056 floats
  float* bufB = ws + o;   o += (size_t)4 * 128 * 112 * 112;  // 6,422,528 floats
  float* bufA2 = bufA + 6422528;  // second half of bufA (final L2 out region)

  // ---- proposal path ----
  winscores_kernel<<<cdiv(16 * 602, BS), BS, 0, stream>>>(att, s_all, out);
  nms_kernel<<<dim3(16, 2), 64, 0, stream>>>(s_all, idx_i);
  gather_kernel<<<1, 128, 0, stream>>>(idx_i, s_all, boxes, out);
  crop_resize_kernel<<<cdiv(112 * 3 * 112 * 112, BS), BS, 0, stream>>>(x, boxes, wimgs);

  // ---- big encoder: L0-L3 in 4-image chunks, L4 over all 16 ----
  for (int chunk = 0; chunk < 4; ++chunk) {
    int n0 = chunk * 4;
    const float* in0 = x + (size_t)n0 * 3 * 448 * 448;
    // L0 direct: x -> bufA
    conv_layer(in0, W[0], Bv[0], bufA, nullptr, 4, 3, 448, 224, 64, 0, 224 * 224, 224, 0, stream);
    // L1 direct: bufA -> bufB
    conv_layer(bufA, W[1], Bv[1], bufB, nullptr, 4, 64, 224, 112, 128, 0, 112 * 112, 112, 0,
               stream);
    // L2 split2: bufB -> partials bufA[0..6.42M) -> final bufA2
    conv_layer(bufB, W[2], Bv[2], bufA2, bufA, 4, 128, 112, 56, 256, 0, 56 * 56, 56, 0, stream);
    // L3 split4: bufA2 -> partials bufB (exact fit) -> featL3+off
    conv_layer(bufA2, W[3], Bv[3], featL3 + (size_t)n0 * 512 * 784, bufB, 4, 256, 56, 28, 512, 0,
               784, 28, 0, stream);
  }
  // L4 split8 over all 16: featL3 -> partials bufA (exact fit) -> featB
  conv_layer(featL3, W[4], Bv[4], featB, bufA, 16, 512, 28, 14, 512, 0, 196, 14, 0, stream);
  avgpool_kernel<<<cdiv(16 * 512, BS), BS, 0, stream>>>(featB, pooled, 16, 512, 196);
  head_kernel<<<cdiv(16 * 200, BS), BS, 0, stream>>>(pooled, head_w, head_b, out + OFF_LAB, 16);

  // zero padded crop-L3 buffer (9x9 planes) -- featL3 fully consumed by L4 conv above
  zerofill_kernel<<<cdiv(112 * 512 * 81, BS), BS, 0, stream>>>(featL3, 112 * 512 * 81);

  // ---- crop encoder: L0-L3 in 56-crop chunks, L4 over all 112 ----
  for (int chunk = 0; chunk < 2; ++chunk) {
    int c0 = chunk * 56;
    const float* in0 = wimgs + (size_t)c0 * 3 * 112 * 112;
    conv_layer(in0, W[0], Bv[0], bufA, nullptr, 56, 3, 112, 56, 64, 0, 56 * 56, 56, 0, stream);
    conv_layer(bufA, W[1], Bv[1], bufB, nullptr, 56, 64, 56, 28, 128, 0, 784, 28, 0, stream);
    conv_layer(bufB, W[2], Bv[2], bufA2, bufA, 56, 128, 28, 14, 256, 0, 196, 14, 0, stream);
    // crop L3 split4: write padded 9x9 planes at (oh+1, ow+1)
    conv_layer(bufA2, W[3], Bv[3], featL3 + (size_t)c0 * 512 * 81, bufB, 56, 256, 14, 7, 512, 0,
               81, 9, 10, stream);
  }
  // crop L4 split8: padded 9x9 input, pad=0 -> all fast-path
  conv_layer(featL3, W[4], Bv[4], featC, bufA, 112, 512, 9, 4, 512, 0, 16, 4, 0, stream);
  avgpool_kernel<<<cdiv(112 * 512, BS), BS, 0, stream>>>(featC, pooled, 112, 512, 16);
  head_kernel<<<cdiv(112 * 200, BS), BS, 0, stream>>>(pooled, head_w, head_b, out + OFF_LOG, 112);
}

// Round 10
// 1787.354 us; speedup vs baseline: 6.9396x; 5.7186x over previous
//
#include <hip/hip_runtime.h>
#include <hip/hip_bf16.h>
#include <math.h>

// ---------------------------------------------------------------------------
// Classifier_with_Augmentation — bf16 MFMA implicit-GEMM encoder, NHWC padded.
//  outputs (flat float32 in d_out):
//   labels 16x200 @0 | win_scores 16x7 @3200 | win_logits 112x200 @3312
//   indices 16x7 @25712 | all_scores 16x602 @25824 | coordinates 16x7x4 @35456
// ---------------------------------------------------------------------------

#define OFF_LAB 0
#define OFF_WSC 3200
#define OFF_LOG 3312
#define OFF_IDX 25712
#define OFF_ALL 25824
#define OFF_CRD 35456

#define BS 256

typedef __attribute__((ext_vector_type(8))) short short8;
typedef __attribute__((ext_vector_type(4))) float f32x4;

static inline int cdiv(int a, int b) { return (a + b - 1) / b; }

// ---- window geometry ------------------------------------------------------
__device__ __forceinline__ void win_decode(int w, int& rh, int& rw, int& r, int& c) {
  const int RH[6] = {4, 3, 5, 6, 5, 7};
  const int RW[6] = {4, 5, 3, 6, 7, 5};
  int rem = w;
#pragma unroll
  for (int i = 0; i < 6; ++i) {
    int nc = 15 - RW[i];
    int cnt = (15 - RH[i]) * nc;
    if (rem < cnt) { rh = RH[i]; rw = RW[i]; r = rem / nc; c = rem - (rem / nc) * nc; return; }
    rem -= cnt;
  }
  rh = 4; rw = 4; r = 0; c = 0;
}

__device__ __forceinline__ void win_to_box(int w, float* bb) {
  int rh, rw, r, c;
  win_decode(w, rh, rw, r, c);
  bb[0] = r * 32.f;
  bb[1] = c * 32.f;
  bb[2] = (r + rh) * 32.f - 1.f;
  bb[3] = (c + rw) * 32.f - 1.f;
}

// ---- window scores --------------------------------------------------------
__global__ void winscores_kernel(const float* __restrict__ att, float* __restrict__ s_all,
                                 float* __restrict__ out) {
  int idx = blockIdx.x * blockDim.x + threadIdx.x;
  if (idx >= 16 * 602) return;
  int b = idx / 602, w = idx - b * 602;
  int rh, rw, r, c;
  win_decode(w, rh, rw, r, c);
  const float* a = att + b * 196;
  float s = 0.f;
  for (int dr = 0; dr < rh; ++dr)
    for (int dc = 0; dc < rw; ++dc)
      s += a[(r + dr) * 14 + (c + dc)];
  float v = s / (float)(rh * rw);
  s_all[idx] = v;
  out[OFF_ALL + idx] = v;
}

// ---- NMS: one wave per (batch, group) -------------------------------------
__global__ void nms_kernel(const float* __restrict__ s_all, int* __restrict__ idx_i) {
  const int b = blockIdx.x, g = blockIdx.y;
  const int gs = g ? 361 : 0;
  const int cnt = g ? 241 : 361;
  const int nsel = g ? 3 : 4;
  const int obase = b * 7 + (g ? 4 : 0);
  __shared__ float sc[361];
  __shared__ float bx0[361], bx1[361], bx2[361], bx3[361];
  const int tid = threadIdx.x;
  for (int k = tid; k < cnt; k += 64) {
    sc[k] = s_all[b * 602 + gs + k];
    float bb[4];
    win_to_box(gs + k, bb);
    bx0[k] = bb[0]; bx1[k] = bb[1]; bx2[k] = bb[2]; bx3[k] = bb[3];
  }
  __syncthreads();
  for (int it = 0; it < nsel; ++it) {
    float bv = -INFINITY;
    int bi = 0x7fffffff;
    for (int k = tid; k < cnt; k += 64) {
      float v = sc[k];
      if (v > bv || (v == bv && k < bi)) { bv = v; bi = k; }
    }
#pragma unroll
    for (int off = 32; off > 0; off >>= 1) {
      float ov = __shfl_down(bv, off);
      int oi = __shfl_down(bi, off);
      if (ov > bv || (ov == bv && oi < bi)) { bv = ov; bi = oi; }
    }
    bi = __shfl(bi, 0);
    if (tid == 0) idx_i[obase + it] = gs + bi;
    float X0 = bx0[bi], X1 = bx1[bi], X2 = bx2[bi], X3 = bx3[bi];
    float a1 = (X2 - X0 + 1.f) * (X3 - X1 + 1.f);
    __syncthreads();
    for (int k = tid; k < cnt; k += 64) {
      float x0 = fmaxf(X0, bx0[k]);
      float y0 = fmaxf(X1, bx1[k]);
      float x1 = fminf(X2, bx2[k]);
      float y1 = fminf(X3, bx3[k]);
      float inter = fmaxf(x1 - x0 + 1.f, 0.f) * fmaxf(y1 - y0 + 1.f, 0.f);
      float a2 = (bx2[k] - bx0[k] + 1.f) * (bx3[k] - bx1[k] + 1.f);
      float iou = inter / (a1 + a2 - inter);
      if (iou > 0.25f) sc[k] = -INFINITY;
    }
    if (tid == 0) sc[bi] = -INFINITY;
    __syncthreads();
  }
}

// ---- gather ---------------------------------------------------------------
__global__ void gather_kernel(const int* __restrict__ idx_i, const float* __restrict__ s_all,
                              float* __restrict__ boxes, float* __restrict__ out) {
  int t = blockIdx.x * blockDim.x + threadIdx.x;
  if (t >= 112) return;
  int b = t / 7;
  int w = idx_i[t];
  out[OFF_IDX + t] = (float)w;
  out[OFF_WSC + t] = s_all[b * 602 + w];
  float bb[4];
  win_to_box(w, bb);
#pragma unroll
  for (int k = 0; k < 4; ++k) {
    boxes[t * 4 + k] = bb[k];
    out[OFF_CRD + t * 4 + k] = bb[k];
  }
}

// ---- bilinear crop-resize 448 -> 112 (fp32, exact) ------------------------
__global__ void crop_resize_kernel(const float* __restrict__ x, const float* __restrict__ boxes,
                                   float* __restrict__ wimgs) {
  int idx = blockIdx.x * blockDim.x + threadIdx.x;
  const int total = 112 * 3 * 112 * 112;
  if (idx >= total) return;
  int j = idx % 112;
  int i = (idx / 112) % 112;
  int ch = (idx / (112 * 112)) % 3;
  int bp = idx / (3 * 112 * 112);
  int b = bp / 7;
  const float* bx = boxes + bp * 4;
  float t_i = (float)i / 111.0f;
  float t_j = (float)j / 111.0f;
  float rs = bx[0] + (bx[2] - bx[0]) * t_i;
  float cs = bx[1] + (bx[3] - bx[1]) * t_j;
  float r0f = floorf(rs), c0f = floorf(cs);
  float wr = rs - r0f, wc = cs - c0f;
  int r0 = (int)r0f, c0 = (int)c0f;
  int r1 = min(r0 + 1, 447), c1 = min(c0 + 1, 447);
  const float* img = x + ((size_t)b * 3 + ch) * 448 * 448;
  float v00 = img[r0 * 448 + c0], v01 = img[r0 * 448 + c1];
  float v10 = img[r1 * 448 + c0], v11 = img[r1 * 448 + c1];
  float top = (1.f - wc) * v00 + wc * v01;
  float bot = (1.f - wc) * v10 + wc * v11;
  wimgs[idx] = (1.f - wr) * top + wr * bot;
}

// ---- zero fill (bf16, 8 at a time) ----------------------------------------
__global__ void zf8_kernel(uint4* __restrict__ p, int n16) {  // n16 = elems/8
  int idx = blockIdx.x * blockDim.x + threadIdx.x;
  if (idx < n16) p[idx] = make_uint4(0, 0, 0, 0);
}

// ---- weight packing: wpk[t][co][ci] bf16 from fp32 [co][ci][3][3] ---------
__global__ void packw_kernel(const float* __restrict__ w, __hip_bfloat16* __restrict__ dst,
                             int Cout, int Cin) {
  int idx = blockIdx.x * blockDim.x + threadIdx.x;
  int total = Cout * Cin * 9;
  if (idx >= total) return;
  int ci = idx % Cin;
  int rc = idx / Cin;
  int co = rc % Cout;
  int t = rc / Cout;
  dst[idx] = __float2bfloat16(w[((size_t)co * Cin + ci) * 9 + t]);
}

// ---- L0 weight packing: wpk0[co][32] (k = t*3+c, zero-padded to 32) -------
__global__ void packw0_kernel(const float* __restrict__ w, __hip_bfloat16* __restrict__ dst) {
  int idx = blockIdx.x * blockDim.x + threadIdx.x;
  if (idx >= 64 * 32) return;
  int co = idx >> 5, k = idx & 31;
  float v = 0.f;
  if (k < 27) {
    int t = k / 3, c = k - t * 3;
    v = w[((size_t)co * 3 + c) * 9 + t];
  }
  dst[idx] = __float2bfloat16(v);
}

// ---- im2col for Cin=3 layers: A[m][32] bf16 (k = t*3+c, pad=0) ------------
__global__ void im2col3_kernel(const float* __restrict__ x, __hip_bfloat16* __restrict__ A,
                               int N, int Hin, int Hout) {
  int m = blockIdx.x * blockDim.x + threadIdx.x;
  int total = N * Hout * Hout;
  if (m >= total) return;
  int n = m / (Hout * Hout);
  int rem = m - n * (Hout * Hout);
  int oh = rem / Hout, ow = rem - (rem / Hout) * Hout;
  const float* xb = x + (size_t)n * 3 * Hin * Hin;
  __hip_bfloat16* a = A + (size_t)m * 32;
#pragma unroll
  for (int kh = 0; kh < 3; ++kh) {
#pragma unroll
    for (int kw = 0; kw < 3; ++kw) {
      int ih = 2 * oh + kh, iw = 2 * ow + kw;
      bool ok = (ih < Hin) && (iw < Hin);
#pragma unroll
      for (int c = 0; c < 3; ++c) {
        float v = ok ? xb[(size_t)c * Hin * Hin + (size_t)ih * Hin + iw] : 0.f;
        a[(kh * 3 + kw) * 3 + c] = __float2bfloat16(v);
      }
    }
  }
#pragma unroll
  for (int k = 27; k < 32; ++k) a[k] = __float2bfloat16(0.f);
}

// ================= bf16 MFMA conv (implicit GEMM, NHWC padded) ==============
// Wave tile: 32 pixels x 64 co. A: one b128/lane per 16-px subtile per K-step;
// B: wpk[t][co][ci], one b128/lane per co-subtile. No LDS, no barriers.
// Fragment maps (mfma_f32_16x16x32_bf16): A row=l&15, k=(l>>4)*8+j;
// B col=l&15, same k; C/D col=l&15, row=(l>>4)*4+r (m89-verified).
// IM2COL mode: in = A-matrix [M][32], taps=1, Cin=32.
template <bool IM2COL>
__global__ __launch_bounds__(256) void conv_mfma_kernel(
    const __hip_bfloat16* __restrict__ in, const __hip_bfloat16* __restrict__ wpk,
    const float* __restrict__ bias, __hip_bfloat16* __restrict__ outp,
    int M, int Hout, int Wout, int Hp, int Wp, int Cin, int Cout, int pad,
    int Hop, int Wop) {
  const int l = threadIdx.x & 63;
  const int w = threadIdx.x >> 6;
  const int px0 = blockIdx.y * 128 + w * 32;
  if (px0 >= M) return;
  const int co0 = blockIdx.x * 64;
  const int half = l >> 4;
  const int lr = l & 15;
  const int HWo = Hout * Wout;

  int mA0 = px0 + lr;      if (mA0 >= M) mA0 = M - 1;
  int mA1 = px0 + 16 + lr; if (mA1 >= M) mA1 = M - 1;
  const __hip_bfloat16* pA0;
  const __hip_bfloat16* pA1;
  if (IM2COL) {
    pA0 = in + (size_t)mA0 * 32 + half * 8;
    pA1 = in + (size_t)mA1 * 32 + half * 8;
  } else {
    int n0 = mA0 / HWo, r0 = mA0 - n0 * HWo, oh0 = r0 / Wout, ow0 = r0 - (r0 / Wout) * Wout;
    int n1 = mA1 / HWo, r1 = mA1 - n1 * HWo, oh1 = r1 / Wout, ow1 = r1 - (r1 / Wout) * Wout;
    pA0 = in + (((size_t)n0 * Hp + (2 * oh0 - pad + 1)) * Wp + (2 * ow0 - pad + 1)) * Cin +
          half * 8;
    pA1 = in + (((size_t)n1 * Hp + (2 * oh1 - pad + 1)) * Wp + (2 * ow1 - pad + 1)) * Cin +
          half * 8;
  }
  const __hip_bfloat16* pB = wpk + (size_t)(co0 + lr) * Cin + half * 8;
  const size_t sCo = (size_t)Cout * Cin;  // B tap stride

  f32x4 acc[2][4];
#pragma unroll
  for (int ms = 0; ms < 2; ++ms)
#pragma unroll
    for (int s = 0; s < 4; ++s) acc[ms][s] = (f32x4){0.f, 0.f, 0.f, 0.f};

  const int nq = Cin >> 5;
  for (int q = 0; q < nq; ++q) {
    const int q32 = q << 5;
    if (IM2COL) {
      short8 a0 = *(const short8*)(pA0);
      short8 a1 = *(const short8*)(pA1);
#pragma unroll
      for (int s = 0; s < 4; ++s) {
        short8 b = *(const short8*)(pB + (size_t)s * 16 * Cin);
        acc[0][s] = __builtin_amdgcn_mfma_f32_16x16x32_bf16(a0, b, acc[0][s], 0, 0, 0);
        acc[1][s] = __builtin_amdgcn_mfma_f32_16x16x32_bf16(a1, b, acc[1][s], 0, 0, 0);
      }
    } else {
#pragma unroll
      for (int kh = 0; kh < 3; ++kh) {
#pragma unroll
        for (int kw = 0; kw < 3; ++kw) {
          const int dA = (kh * Wp + kw) * Cin + q32;
          short8 a0 = *(const short8*)(pA0 + dA);
          short8 a1 = *(const short8*)(pA1 + dA);
          const __hip_bfloat16* qb = pB + (size_t)(kh * 3 + kw) * sCo + q32;
#pragma unroll
          for (int s = 0; s < 4; ++s) {
            short8 b = *(const short8*)(qb + (size_t)s * 16 * Cin);
            acc[0][s] = __builtin_amdgcn_mfma_f32_16x16x32_bf16(a0, b, acc[0][s], 0, 0, 0);
            acc[1][s] = __builtin_amdgcn_mfma_f32_16x16x32_bf16(a1, b, acc[1][s], 0, 0, 0);
          }
        }
      }
    }
  }

  float bj0 = bias[co0 + lr];
  float bj1 = bias[co0 + 16 + lr];
  float bj2 = bias[co0 + 32 + lr];
  float bj3 = bias[co0 + 48 + lr];
#pragma unroll
  for (int ms = 0; ms < 2; ++ms) {
#pragma unroll
    for (int r = 0; r < 4; ++r) {
      int m = px0 + ms * 16 + half * 4 + r;
      if (m >= M) continue;
      int n = m / HWo, rem = m - n * HWo;
      int oh = rem / Wout, ow = rem - (rem / Wout) * Wout;
      __hip_bfloat16* ob =
          outp + (((size_t)n * Hop + oh + 1) * Wop + (ow + 1)) * Cout + co0 + lr;
      float v0 = fmaxf(acc[ms][0][r] + bj0, 0.f);
      float v1 = fmaxf(acc[ms][1][r] + bj1, 0.f);
      float v2 = fmaxf(acc[ms][2][r] + bj2, 0.f);
      float v3 = fmaxf(acc[ms][3][r] + bj3, 0.f);
      ob[0] = __float2bfloat16(v0);
      ob[16] = __float2bfloat16(v1);
      ob[32] = __float2bfloat16(v2);
      ob[48] = __float2bfloat16(v3);
    }
  }
}

// ---- mean pool over NHWC padded interior ----------------------------------
__global__ void avgpool_nhwc_kernel(const __hip_bfloat16* __restrict__ feat,
                                    float* __restrict__ pooled, int Nimg, int H, int Hp, int C) {
  int idx = blockIdx.x * blockDim.x + threadIdx.x;
  if (idx >= Nimg * C) return;
  int n = idx / C, c = idx - n * C;
  float s = 0.f;
  for (int h = 1; h <= H; ++h)
    for (int ww = 1; ww <= H; ++ww)
      s += __bfloat162float(feat[(((size_t)n * Hp + h) * Hp + ww) * C + c]);
  pooled[idx] = s / (float)(H * H);
}

// ---- head GEMM (fp32) -----------------------------------------------------
__global__ void head_kernel(const float* __restrict__ pooled, const float* __restrict__ hw,
                            const float* __restrict__ hb, float* __restrict__ outp, int M) {
  int idx = blockIdx.x * blockDim.x + threadIdx.x;
  if (idx >= M * 200) return;
  int m = idx / 200, c = idx - m * 200;
  float acc = hb[c];
  const float* pm = pooled + m * 512;
  for (int k = 0; k < 512; ++k) acc = fmaf(pm[k], hw[k * 200 + c], acc);
  outp[idx] = acc;
}

// ---------------------------------------------------------------------------
static void launch_conv(bool im2col, const __hip_bfloat16* in, const __hip_bfloat16* wpk,
                        const float* bv, __hip_bfloat16* dst, int M, int Hout, int Hp, int Cin,
                        int Cout, int pad, int Hop, hipStream_t s) {
  dim3 grid(Cout / 64, cdiv(M, 128));
  if (im2col)
    conv_mfma_kernel<true><<<grid, 256, 0, s>>>(in, wpk, bv, dst, M, Hout, Hout, Hp, Hp, Cin,
                                                Cout, pad, Hop, Hop);
  else
    conv_mfma_kernel<false><<<grid, 256, 0, s>>>(in, wpk, bv, dst, M, Hout, Hout, Hp, Hp, Cin,
                                                 Cout, pad, Hop, Hop);
}

static void zf(__hip_bfloat16* p, size_t n, hipStream_t s) {  // n multiple of 8
  zf8_kernel<<<cdiv((int)(n / 8), BS), BS, 0, s>>>((uint4*)p, (int)(n / 8));
}

extern "C" void kernel_launch(void* const* d_in, const int* in_sizes, int n_in,
                              void* d_out, int out_size, void* d_ws, size_t ws_size,
                              hipStream_t stream) {
  const float* x = (const float*)d_in[0];
  const float* att = (const float*)d_in[1];
  const float* W[5] = {(const float*)d_in[2], (const float*)d_in[4], (const float*)d_in[6],
                       (const float*)d_in[8], (const float*)d_in[10]};
  const float* Bv[5] = {(const float*)d_in[3], (const float*)d_in[5], (const float*)d_in[7],
                        (const float*)d_in[9], (const float*)d_in[11]};
  const float* head_w = (const float*)d_in[12];
  const float* head_b = (const float*)d_in[13];
  float* out = (float*)d_out;
  float* ws = (float*)d_ws;

  // ---- workspace: fp32 region, then bf16 region (~117MB total) ----
  size_t o = 0;
  float* s_all = ws + o;  o += 16 * 602;
  int* idx_i = (int*)(ws + o); o += 112;
  float* boxes = ws + o;  o += 112 * 4;
  float* pooled = ws + o; o += (size_t)112 * 512;
  float* wimgs = ws + o;  o += (size_t)112 * 3 * 112 * 112;
  __hip_bfloat16* hb = (__hip_bfloat16*)(ws + o);
  size_t h = 0;
  __hip_bfloat16* wpk0 = hb + h; h += 64 * 32;
  __hip_bfloat16* wpk1 = hb + h; h += (size_t)9 * 128 * 64;
  __hip_bfloat16* wpk2 = hb + h; h += (size_t)9 * 256 * 128;
  __hip_bfloat16* wpk3 = hb + h; h += (size_t)9 * 512 * 256;
  __hip_bfloat16* wpk4 = hb + h; h += (size_t)9 * 512 * 512;
  __hip_bfloat16* A_L0 = hb + h; h += (size_t)200704 * 32;          // 6.42M
  __hip_bfloat16* bufA = hb + h; h += (size_t)4 * 226 * 226 * 64;   // 13.08M
  __hip_bfloat16* bufB = hb + h; h += (size_t)4 * 114 * 114 * 128;  // 6.65M
  __hip_bfloat16* bufC = hb + h; h += (size_t)56 * 16 * 16 * 256;   // 3.67M (>= big L2 3.44M)
  __hip_bfloat16* fL3b = hb + h; h += (size_t)16 * 30 * 30 * 512;   // 7.37M
  __hip_bfloat16* fL3c = hb + h; h += (size_t)112 * 9 * 9 * 512;    // 4.64M
  __hip_bfloat16* featB = hb + h; h += (size_t)16 * 16 * 16 * 512;  // 2.10M
  __hip_bfloat16* featC = hb + h; h += (size_t)112 * 6 * 6 * 512;   // 2.06M

  // ---- proposal path (fp32, exact) ----
  winscores_kernel<<<cdiv(16 * 602, BS), BS, 0, stream>>>(att, s_all, out);
  nms_kernel<<<dim3(16, 2), 64, 0, stream>>>(s_all, idx_i);
  gather_kernel<<<1, 128, 0, stream>>>(idx_i, s_all, boxes, out);
  crop_resize_kernel<<<cdiv(112 * 3 * 112 * 112, BS), BS, 0, stream>>>(x, boxes, wimgs);

  // ---- pack weights ----
  packw0_kernel<<<cdiv(64 * 32, BS), BS, 0, stream>>>(W[0], wpk0);
  packw_kernel<<<cdiv(9 * 128 * 64, BS), BS, 0, stream>>>(W[1], wpk1, 128, 64);
  packw_kernel<<<cdiv(9 * 256 * 128, BS), BS, 0, stream>>>(W[2], wpk2, 256, 128);
  packw_kernel<<<cdiv(9 * 512 * 256, BS), BS, 0, stream>>>(W[3], wpk3, 512, 256);
  packw_kernel<<<cdiv(9 * 512 * 512, BS), BS, 0, stream>>>(W[4], wpk4, 512, 512);

  // ---- big encoder: L0-L3 in 4-image chunks, L4 over all 16 ----
  zf(bufA, (size_t)4 * 226 * 226 * 64, stream);
  zf(bufB, (size_t)4 * 114 * 114 * 128, stream);
  zf(bufC, (size_t)56 * 16 * 16 * 256, stream);
  zf(fL3b, (size_t)16 * 30 * 30 * 512, stream);
  zf(featB, (size_t)16 * 16 * 16 * 512, stream);
  for (int chunk = 0; chunk < 4; ++chunk) {
    int n0 = chunk * 4;
    im2col3_kernel<<<cdiv(200704, BS), BS, 0, stream>>>(x + (size_t)n0 * 3 * 448 * 448, A_L0, 4,
                                                        448, 224);
    launch_conv(true, A_L0, wpk0, Bv[0], bufA, 200704, 224, 0, 32, 64, 0, 226, stream);
    launch_conv(false, bufA, wpk1, Bv[1], bufB, 50176, 112, 226, 64, 128, 0, 114, stream);
    launch_conv(false, bufB, wpk2, Bv[2], bufC, 12544, 56, 114, 128, 256, 0, 58, stream);
    launch_conv(false, bufC, wpk3, Bv[3], fL3b + (size_t)n0 * 30 * 30 * 512, 3136, 28, 58, 256,
                512, 0, 30, stream);
  }
  launch_conv(false, fL3b, wpk4, Bv[4], featB, 16 * 196, 14, 30, 512, 512, 0, 16, stream);
  avgpool_nhwc_kernel<<<cdiv(16 * 512, BS), BS, 0, stream>>>(featB, pooled, 16, 14, 16, 512);
  head_kernel<<<cdiv(16 * 200, BS), BS, 0, stream>>>(pooled, head_w, head_b, out + OFF_LAB, 16);

  // ---- crop encoder: L0-L3 in 56-crop chunks, L4 over all 112 ----
  zf(bufA, (size_t)4 * 226 * 226 * 64, stream);
  zf(bufB, (size_t)4 * 114 * 114 * 128, stream);
  zf(bufC, (size_t)56 * 16 * 16 * 256, stream);
  zf(fL3c, (size_t)112 * 9 * 9 * 512, stream);
  zf(featC, (size_t)112 * 6 * 6 * 512, stream);
  for (int chunk = 0; chunk < 2; ++chunk) {
    int c0 = chunk * 56;
    im2col3_kernel<<<cdiv(175616, BS), BS, 0, stream>>>(wimgs + (size_t)c0 * 3 * 112 * 112, A_L0,
                                                        56, 112, 56);
    launch_conv(true, A_L0, wpk0, Bv[0], bufA, 175616, 56, 0, 32, 64, 0, 58, stream);
    launch_conv(false, bufA, wpk1, Bv[1], bufB, 43904, 28, 58, 64, 128, 0, 30, stream);
    launch_conv(false, bufB, wpk2, Bv[2], bufC, 10976, 14, 30, 128, 256, 0, 16, stream);
    launch_conv(false, bufC, wpk3, Bv[3], fL3c + (size_t)c0 * 9 * 9 * 512, 2744, 7, 16, 256, 512,
                0, 9, stream);
  }
  launch_conv(false, fL3c, wpk4, Bv[4], featC, 112 * 16, 4, 9, 512, 512, 1, 6, stream);
  avgpool_nhwc_kernel<<<cdiv(112 * 512, BS), BS, 0, stream>>>(featC, pooled, 112, 4, 6, 512);
  head_kernel<<<cdiv(112 * 200, BS), BS, 0, stream>>>(pooled, head_w, head_b, out + OFF_LOG, 112);
}